// Round 3
// baseline (17506.625 us; speedup 1.0000x reference)
//
#include <hip/hip_runtime.h>
#include <math.h>

#define N_NODES 20000
#define D_INN   512
#define DH      256
#define NCH     7
#define NE      320000
#define NE2     100000
#define NB      8192
#define H3      2304   // 512 + 7*256
#define MAXN    0.996f

typedef unsigned short u16;
typedef __attribute__((ext_vector_type(8))) short bf16x8;
typedef __attribute__((ext_vector_type(4))) float f32x4;

__device__ __forceinline__ u16 f2b(float f) {    // RNE f32 -> bf16 bits
    unsigned int x = __float_as_uint(f);
    unsigned int r = (x + 0x7fffu + ((x >> 16) & 1u)) >> 16;
    return (u16)r;
}
__device__ __forceinline__ float b2f(u16 u) {
    return __uint_as_float(((unsigned int)u) << 16);
}

__device__ __forceinline__ float artanh_f(float x) {
    x = fminf(fmaxf(x, -1.0f + 1e-7f), 1.0f - 1e-7f);
    return 0.5f * (log1pf(x) - log1pf(-x));
}

__device__ __forceinline__ float block_sum256(float v) {
    __shared__ float sred[4];
    #pragma unroll
    for (int off = 32; off > 0; off >>= 1) v += __shfl_down(v, off, 64);
    int lane = threadIdx.x & 63;
    int w = threadIdx.x >> 6;
    if (lane == 0) sred[w] = v;
    __syncthreads();
    float tot = sred[0] + sred[1] + sred[2] + sred[3];
    __syncthreads();
    return tot;
}

__global__ void k_zero(float* __restrict__ p, int n) {
    int i = blockIdx.x * 256 + threadIdx.x;
    if (i < n) p[i] = 0.0f;
}

// f32 -> bf16 convert, 4 elems/thread, grid-stride (n4 = n/4)
__global__ void k_f2b(const float* __restrict__ s, u16* __restrict__ d, int n4) {
    int i = blockIdx.x * 256 + threadIdx.x;
    int stride = gridDim.x * 256;
    for (; i < n4; i += stride) {
        float4 v = ((const float4*)s)[i];
        unsigned int lo = (unsigned int)f2b(v.x) | ((unsigned int)f2b(v.y) << 16);
        unsigned int hi = (unsigned int)f2b(v.z) | ((unsigned int)f2b(v.w) << 16);
        uint2 o; o.x = lo; o.y = hi;
        ((uint2*)d)[i] = o;
    }
}

// x_hyp = proj(expmap0(f1)) -> bf16; clamped row norm -> xhn (f32)
__global__ void k_expmap_proj_in(const float* __restrict__ f1,
                                 u16* __restrict__ xhyp, float* __restrict__ xhn) {
    int r = blockIdx.x, t = threadIdx.x;
    const float* u = f1 + (size_t)r * D_INN;
    float v0 = u[t], v1 = u[t + 256];
    float ss = block_sum256(v0 * v0 + v1 * v1);
    float nraw = sqrtf(ss);
    float n = fmaxf(nraw, 1e-15f);
    float c = tanhf(n) / n;
    float ny = c * nraw;
    float np = fmaxf(ny, 1e-15f);
    float s = (np > MAXN) ? MAXN / np : 1.0f;
    float cs = c * s;
    u16* o = xhyp + (size_t)r * D_INN;
    o[t] = f2b(cs * v0);
    o[t + 256] = f2b(cs * v1);
    if (t == 0) xhn[r] = fminf(np, MAXN);
}

__global__ void k_hb(const float* __restrict__ b_hyp,
                     float* __restrict__ hb, float* __restrict__ hb2) {
    int i = blockIdx.x, t = threadIdx.x;
    float v = b_hyp[i * DH + t];
    float ss = block_sum256(v * v);
    float nraw = sqrtf(ss);
    float n = fmaxf(nraw, 1e-15f);
    float c = tanhf(n) / n;
    float ny = c * nraw;
    float np = fmaxf(ny, 1e-15f);
    float s = (np > MAXN) ? MAXN / np : 1.0f;
    float hv = c * s * v;
    hb[i * DH + t] = hv;
    float s2 = block_sum256(hv * hv);
    if (t == 0) hb2[i] = s2;
}

// in-place f32 on T1 row: mobius_matvec finalize -> proj -> mobius_add(hb) -> proj -> logmap0
__global__ void k_rowfuse1(float* __restrict__ T1, const float* __restrict__ xhn,
                           const float* __restrict__ hb, const float* __restrict__ hb2) {
    int r = blockIdx.x, t = threadIdx.x;
    float* row = T1 + (size_t)r * DH;
    float m = row[t];
    float ss = block_sum256(m * m);
    float mxn_raw = sqrtf(ss);
    float mxn = fmaxf(mxn_raw, 1e-15f);
    float xn = xhn[r];
    float tt = tanhf(mxn / xn * artanh_f(xn));
    float coef = tt / mxn;
    float res = coef * m;
    float nres = coef * mxn_raw;
    float np = fmaxf(nres, 1e-15f);
    float s1 = (np > MAXN) ? MAXN / np : 1.0f;
    res *= s1;
    float n1 = fminf(np, MAXN);
    float hbv = hb[t];
    float xy = block_sum256(res * hbv);
    float x2 = n1 * n1, y2 = hb2[0];
    float num = (1.0f + 2.0f * xy + y2) * res + (1.0f - x2) * hbv;
    float den = fmaxf(1.0f + 2.0f * xy + x2 * y2, 1e-15f);
    float o = num / den;
    float no2 = block_sum256(o * o);
    float nop = fmaxf(sqrtf(no2), 1e-15f);
    float s2 = (nop > MAXN) ? MAXN / nop : 1.0f;
    float p = o * s2;
    float n2 = fminf(nop, MAXN);
    row[t] = artanh_f(n2) / n2 * p;
}

// reads support (f32), full hyperbolic chain, writes u as bf16
__global__ void k_rowfuse2(const float* __restrict__ T2, u16* __restrict__ out) {
    int r = blockIdx.x, t = threadIdx.x;
    float sv = T2[(size_t)r * DH + t];
    float ss = block_sum256(sv * sv);
    float nraw = sqrtf(ss);
    float n = fmaxf(nraw, 1e-15f);
    float c1 = tanhf(n) / n;
    float h = c1 * sv;
    float nh = c1 * nraw;
    float np1 = fmaxf(nh, 1e-15f);
    float s1 = (np1 > MAXN) ? MAXN / np1 : 1.0f;
    h *= s1;
    float n1 = fminf(np1, MAXN);
    float u = artanh_f(n1) / n1 * h;
    u = fmaxf(u, 0.0f);
    float ss2 = block_sum256(u * u);
    float n2raw = sqrtf(ss2);
    float n2 = fmaxf(n2raw, 1e-15f);
    float c3 = tanhf(n2) / n2;
    float e = c3 * u;
    float ne = c3 * n2raw;
    float np3 = fmaxf(ne, 1e-15f);
    float s3 = (np3 > MAXN) ? MAXN / np3 : 1.0f;
    e *= s3;
    float n3 = fminf(np3, MAXN);
    out[(size_t)r * DH + t] = f2b(artanh_f(n3) / n3 * e);
}

// 4 edges/block (one per wave); lane handles 4 consecutive floats
__global__ void k_scatter_scale(const int* __restrict__ src, const int* __restrict__ dst,
                                const float* __restrict__ val, const float* __restrict__ xt,
                                float* __restrict__ sup) {
    int w = threadIdx.x >> 6, lane = threadIdx.x & 63;
    int e = blockIdx.x * 4 + w;
    int s = src[e], d = dst[e];
    float v = val[e];
    float4 x = *(const float4*)(xt + (size_t)s * DH + lane * 4);
    float* o = sup + (size_t)d * DH + lane * 4;
    atomicAdd(o + 0, v * x.x);
    atomicAdd(o + 1, v * x.y);
    atomicAdd(o + 2, v * x.z);
    atomicAdd(o + 3, v * x.w);
}

__global__ void k_scatter_add(const int* __restrict__ src, const int* __restrict__ dst,
                              const float* __restrict__ dv, float* __restrict__ agg) {
    int w = threadIdx.x >> 6, lane = threadIdx.x & 63;
    int e = blockIdx.x * 4 + w;
    int s = src[e], d = dst[e];
    float4 x = *(const float4*)(dv + (size_t)s * DH + lane * 4);
    float* o = agg + (size_t)d * DH + lane * 4;
    atomicAdd(o + 0, x.x);
    atomicAdd(o + 1, x.y);
    atomicAdd(o + 2, x.z);
    atomicAdd(o + 3, x.w);
}

__global__ void k_colstats(const float* __restrict__ z,
                           float* __restrict__ csum, float* __restrict__ csq) {
    int t = threadIdx.x;
    int r0 = blockIdx.x * 100;
    float s = 0.0f, q = 0.0f;
    for (int r = r0; r < r0 + 100; ++r) {
        float v = z[(size_t)r * DH + t];
        s += v;
        q += v * v;
    }
    atomicAdd(&csum[t], s);
    atomicAdd(&csq[t], q);
}

// batchnorm + tanh; writes bf16
__global__ void k_normtanh(const float* __restrict__ z, u16* __restrict__ out,
                           const float* __restrict__ csum, const float* __restrict__ csq,
                           const float* __restrict__ gamma, const float* __restrict__ beta) {
    int idx = blockIdx.x * 256 + threadIdx.x;
    int j = idx & 255;
    float mu = csum[j] * (1.0f / N_NODES);
    float var = csq[j] * (1.0f / N_NODES) - mu * mu;
    float inv = 1.0f / sqrtf(var + 1e-5f);
    float v = (z[idx] - mu) * inv * gamma[j] + beta[j];
    out[idx] = f2b(tanhf(v));
}

// f1 slice of S,P (cols 0..511)
__global__ void k_pair0(const int* __restrict__ ei, const int* __restrict__ eid,
                        const float* __restrict__ f1, u16* __restrict__ S,
                        u16* __restrict__ P) {
    int b = blockIdx.x, t = threadIdx.x;
    int e = eid[b];
    int n0 = ei[e], n1 = ei[NE2 + e];
    const float* xa = f1 + (size_t)n0 * D_INN;
    const float* xb = f1 + (size_t)n1 * D_INN;
    u16* so = S + (size_t)b * H3;
    u16* po = P + (size_t)b * H3;
    for (int j = t; j < D_INN; j += 256) {
        float a = xa[j], c = xb[j];
        so[j] = f2b(a + c);
        po[j] = f2b(a * c);
    }
}

// channel slice of S,P gathered from z_ch (bf16, 20000x256)
__global__ void k_gather_ch(const int* __restrict__ ei, const int* __restrict__ eid,
                            const u16* __restrict__ z, u16* __restrict__ S,
                            u16* __restrict__ P, int col0) {
    int b = blockIdx.x, j = threadIdx.x;
    int e = eid[b];
    int n0 = ei[e], n1 = ei[NE2 + e];
    float a = b2f(z[(size_t)n0 * DH + j]);
    float c = b2f(z[(size_t)n1 * DH + j]);
    S[(size_t)b * H3 + col0 + j] = f2b(a + c);
    P[(size_t)b * H3 + col0 + j] = f2b(a * c);
}

__global__ void k_final(const float* __restrict__ h2, const float* __restrict__ Wf3,
                        const float* __restrict__ bf3, float* __restrict__ out) {
    int r = blockIdx.x, t = threadIdx.x;
    const float* hr = h2 + (size_t)r * 576;
    float acc[7] = {0, 0, 0, 0, 0, 0, 0};
    for (int cb = t; cb < 576; cb += 64) {
        float h = hr[cb];
        #pragma unroll
        for (int o = 0; o < 7; ++o) acc[o] = fmaf(h, Wf3[o * 576 + cb], acc[o]);
    }
    #pragma unroll
    for (int o = 0; o < 7; ++o) {
        #pragma unroll
        for (int off = 32; off > 0; off >>= 1) acc[o] += __shfl_down(acc[o], off, 64);
    }
    if (t == 0) {
        #pragma unroll
        for (int o = 0; o < 7; ++o) out[(size_t)r * 7 + o] = acc[o] + bf3[o];
    }
}

// ===== bf16 MFMA GEMM: C[M,N] = A[M,K] @ W[N,K]^T (+bias), A/W bf16 row-major.
// 128x128 tile, BK=32, 256 thr (4 waves, 2x2), 16x16x32 MFMA, 4x4 frags/wave.
// LDS tiles stored in fragment order [rowgrp][kchunk][r16][8bf16] so both the
// ds_write (staging) and ds_read_b128 (frag fetch, addr = base + lane*16B) are
// linear and bank-conflict-free.
// EP: 0=f32, 1=dual-f32, 2=sigmoid->bf16, 3=relu->bf16, 4=aux*relu->bf16,
//     5=bf16, 6=relu->f32
template <int EP>
__global__ __launch_bounds__(256, 2) void k_gemm_mfma(
    const u16* __restrict__ A, const u16* __restrict__ W,
    const float* __restrict__ bias, void* __restrict__ outv,
    void* __restrict__ out2v, const u16* __restrict__ aux,
    int M, int N, int K) {
    __shared__ short As[4096];   // 128x32 bf16
    __shared__ short Ws[4096];
    const int t = threadIdx.x;
    const int lane = t & 63;
    const int w = t >> 6;
    const int wr = w >> 1, wc = w & 1;
    const int row0 = blockIdx.y * 128, col0 = blockIdx.x * 128;
    f32x4 acc[4][4] = {};
    for (int k0 = 0; k0 < K; k0 += 32) {
        #pragma unroll
        for (int p = 0; p < 2; ++p) {
            int i = t + p * 256;               // 0..511
            int row = i >> 2, kc = i & 3;
            int gr = row0 + row; gr = (gr < M) ? gr : (M - 1);
            int gc = col0 + row; gc = (gc < N) ? gc : (N - 1);
            uint4 va = *(const uint4*)(A + (size_t)gr * K + k0 + kc * 8);
            uint4 vw = *(const uint4*)(W + (size_t)gc * K + k0 + kc * 8);
            int off = (row >> 4) * 512 + kc * 128 + (row & 15) * 8;  // shorts
            *(uint4*)(As + off) = va;
            *(uint4*)(Ws + off) = vw;
        }
        __syncthreads();
        bf16x8 af[4], bfr[4];
        #pragma unroll
        for (int m = 0; m < 4; ++m)
            af[m] = *(const bf16x8*)(As + (wr * 4 + m) * 512 + lane * 8);
        #pragma unroll
        for (int n = 0; n < 4; ++n)
            bfr[n] = *(const bf16x8*)(Ws + (wc * 4 + n) * 512 + lane * 8);
        #pragma unroll
        for (int m = 0; m < 4; ++m)
            #pragma unroll
            for (int n = 0; n < 4; ++n)
                acc[m][n] = __builtin_amdgcn_mfma_f32_16x16x32_bf16(af[m], bfr[n], acc[m][n], 0, 0, 0);
        __syncthreads();
    }
    // epilogue: C/D frag layout col=lane&15, row=(lane>>4)*4+reg [m89-verified]
    const int cl = lane & 15, rh = (lane >> 4) * 4;
    #pragma unroll
    for (int m = 0; m < 4; ++m) {
        #pragma unroll
        for (int n = 0; n < 4; ++n) {
            int col = col0 + wc * 64 + n * 16 + cl;
            if (col >= N) continue;
            float bv = bias ? bias[col] : 0.0f;
            #pragma unroll
            for (int r = 0; r < 4; ++r) {
                int row = row0 + wr * 64 + m * 16 + rh + r;
                if (row >= M) continue;
                float v = acc[m][n][r] + bv;
                size_t idx = (size_t)row * N + col;
                if (EP == 0) ((float*)outv)[idx] = v;
                if (EP == 1) { ((float*)outv)[idx] = v; ((float*)out2v)[idx] = v; }
                if (EP == 2) ((u16*)outv)[idx] = f2b(1.0f / (1.0f + expf(-v)));
                if (EP == 3) ((u16*)outv)[idx] = f2b(fmaxf(v, 0.0f));
                if (EP == 4) { float g = b2f(aux[idx]); ((u16*)outv)[idx] = f2b(g * fmaxf(v, 0.0f)); }
                if (EP == 5) ((u16*)outv)[idx] = f2b(v);
                if (EP == 6) ((float*)outv)[idx] = fmaxf(v, 0.0f);
            }
        }
    }
}

static inline void gemm_b(int ep, const u16* A, const u16* W, const float* bias, void* out,
                          void* out2, const u16* aux, int M, int N, int K, hipStream_t st) {
    dim3 g((N + 127) / 128, (M + 127) / 128);
    switch (ep) {
        case 0: k_gemm_mfma<0><<<g, 256, 0, st>>>(A, W, bias, out, out2, aux, M, N, K); break;
        case 1: k_gemm_mfma<1><<<g, 256, 0, st>>>(A, W, bias, out, out2, aux, M, N, K); break;
        case 2: k_gemm_mfma<2><<<g, 256, 0, st>>>(A, W, bias, out, out2, aux, M, N, K); break;
        case 3: k_gemm_mfma<3><<<g, 256, 0, st>>>(A, W, bias, out, out2, aux, M, N, K); break;
        case 4: k_gemm_mfma<4><<<g, 256, 0, st>>>(A, W, bias, out, out2, aux, M, N, K); break;
        case 5: k_gemm_mfma<5><<<g, 256, 0, st>>>(A, W, bias, out, out2, aux, M, N, K); break;
        case 6: k_gemm_mfma<6><<<g, 256, 0, st>>>(A, W, bias, out, out2, aux, M, N, K); break;
    }
}

static inline void conv_w(const float* s, u16* d, size_t n, hipStream_t st) {
    int n4 = (int)(n / 4);
    int grid = (n4 + 255) / 256;
    if (grid > 2048) grid = 2048;
    k_f2b<<<grid, 256, 0, st>>>(s, d, n4);
}

extern "C" void kernel_launch(void* const* d_in, const int* in_sizes, int n_in, void* d_out,
                              int out_size, void* d_ws, size_t ws_size, hipStream_t stream) {
    const float* f1 = (const float*)d_in[0];
    const int* adj_src = (const int*)d_in[1];
    const int* adj_dst = (const int*)d_in[2];
    const float* adj_val = (const float*)d_in[3];
    const int* edge_src = (const int*)d_in[4];
    const int* edge_dst = (const int*)d_in[5];
    const int* edge_index = (const int*)d_in[6];
    const int* edge_id = (const int*)d_in[7];
    const float* W_hyp = (const float*)d_in[8];
    const float* b_hyp = (const float*)d_in[9];
    const float* Wd = (const float*)d_in[10];
    const float* bd = (const float*)d_in[11];
    const float* Wg1 = (const float*)d_in[12];
    const float* bg1 = (const float*)d_in[13];
    const float* gamma = (const float*)d_in[14];
    const float* beta = (const float*)d_in[15];
    const float* Wg2 = (const float*)d_in[16];
    const float* bg2 = (const float*)d_in[17];
    const float* Wgate = (const float*)d_in[18];
    const float* bgate = (const float*)d_in[19];
    const float* Wint = (const float*)d_in[20];
    const float* bint = (const float*)d_in[21];
    const float* Wout = (const float*)d_in[22];
    const float* bout = (const float*)d_in[23];
    const float* Wf1 = (const float*)d_in[24];
    const float* bf1 = (const float*)d_in[25];
    const float* Wf2 = (const float*)d_in[26];
    const float* bf2 = (const float*)d_in[27];
    const float* Wf3 = (const float*)d_in[28];
    const float* bf3 = (const float*)d_in[29];
    float* outp = (float*)d_out;

    // ---- workspace bump allocator (total ~248.6 MB) ----
    char* base = (char*)d_ws;
    size_t off = 0;
    auto alloc = [&](size_t bytes) -> char* {
        char* p = base + off;
        off += (bytes + 255) & ~(size_t)255;
        return p;
    };
    u16* Whyp_b = (u16*)alloc((size_t)NCH * DH * D_INN * 2);
    u16* Wd_b   = (u16*)alloc((size_t)NCH * DH * DH * 2);
    u16* Wg1_b  = (u16*)alloc((size_t)NCH * DH * DH * 2);
    u16* Wg2_b  = (u16*)alloc((size_t)NCH * DH * DH * 2);
    u16* Wgate_b = (u16*)alloc((size_t)H3 * H3 * 2);
    u16* Wint_b  = (u16*)alloc((size_t)H3 * H3 * 2);
    u16* Wout_b  = (u16*)alloc((size_t)H3 * H3 * 2);
    u16* Wf1_b   = (u16*)alloc((size_t)1152 * H3 * 2);
    u16* Wf2_b   = (u16*)alloc((size_t)576 * 1152 * 2);
    u16* S_b = (u16*)alloc((size_t)NB * H3 * 2);
    u16* P_b = (u16*)alloc((size_t)NB * H3 * 2);
    u16* G_b = (u16*)alloc((size_t)NB * H3 * 2);       // gate; later h1 (8192x1152)
    char* pool = alloc((size_t)N_NODES * D_INN * 2      // xhyp_b
                       + 3 * (size_t)N_NODES * DH * 4   // T1f,T2f,T3f
                       + (size_t)N_NODES * DH * 2);     // Tb
    u16* xhyp_b = (u16*)pool;
    float* T1f = (float*)(pool + (size_t)N_NODES * D_INN * 2);
    float* T2f = T1f + (size_t)N_NODES * DH;
    float* T3f = T2f + (size_t)N_NODES * DH;
    u16* Tb = (u16*)(T3f + (size_t)N_NODES * DH);
    u16* Zb = (u16*)T2f;                 // z_ch bf16, reuses T2f (dead by then)
    float* h2f = (float*)pool;           // stage-C h2 (8192x576 f32), pool dead
    float* xhn = (float*)alloc((size_t)N_NODES * 4);
    float* hb = (float*)alloc((size_t)NCH * DH * 4);
    float* hb2 = (float*)alloc(NCH * 4);
    float* csum = (float*)alloc(DH * 4);
    float* csq = (float*)alloc(DH * 4);

    // weight conversions (once per launch)
    conv_w(W_hyp, Whyp_b, (size_t)NCH * DH * D_INN, stream);
    conv_w(Wd, Wd_b, (size_t)NCH * DH * DH, stream);
    conv_w(Wg1, Wg1_b, (size_t)NCH * DH * DH, stream);
    conv_w(Wg2, Wg2_b, (size_t)NCH * DH * DH, stream);
    conv_w(Wgate, Wgate_b, (size_t)H3 * H3, stream);
    conv_w(Wint, Wint_b, (size_t)H3 * H3, stream);
    conv_w(Wout, Wout_b, (size_t)H3 * H3, stream);
    conv_w(Wf1, Wf1_b, (size_t)1152 * H3, stream);
    conv_w(Wf2, Wf2_b, (size_t)576 * 1152, stream);

    k_expmap_proj_in<<<N_NODES, 256, 0, stream>>>(f1, xhyp_b, xhn);
    k_hb<<<NCH, 256, 0, stream>>>(b_hyp, hb, hb2);
    k_pair0<<<NB, 256, 0, stream>>>(edge_index, edge_id, f1, S_b, P_b);

    for (int ch = 0; ch < NCH; ++ch) {
        // mx = x_hyp @ W_hyp[ch].T  -> T1f (f32)
        gemm_b(0, xhyp_b, Whyp_b + (size_t)ch * DH * D_INN, nullptr, T1f, nullptr, nullptr,
               N_NODES, DH, D_INN, stream);
        k_rowfuse1<<<N_NODES, 256, 0, stream>>>(T1f, xhn, hb + ch * DH, hb2 + ch);
        k_zero<<<(N_NODES * DH) / 256, 256, 0, stream>>>(T2f, N_NODES * DH);
        k_scatter_scale<<<NE / 4, 256, 0, stream>>>(adj_src + (size_t)ch * NE,
                                                    adj_dst + (size_t)ch * NE,
                                                    adj_val + (size_t)ch * NE, T1f, T2f);
        k_rowfuse2<<<N_NODES, 256, 0, stream>>>(T2f, Tb);
        // d = u @ Wd.T + bd -> T1f (scatter src) and T3f (agg init), f32
        gemm_b(1, Tb, Wd_b + (size_t)ch * DH * DH, bd + ch * DH, T1f, T3f, nullptr,
               N_NODES, DH, DH, stream);
        k_scatter_add<<<NE / 4, 256, 0, stream>>>(edge_src + (size_t)ch * NE,
                                                  edge_dst + (size_t)ch * NE, T1f, T3f);
        conv_w(T3f, Tb, (size_t)N_NODES * DH, stream);   // agg -> bf16
        // z = agg @ Wg1.T + bg1 -> T1f (f32)
        gemm_b(0, Tb, Wg1_b + (size_t)ch * DH * DH, bg1 + ch * DH, T1f, nullptr, nullptr,
               N_NODES, DH, DH, stream);
        k_zero<<<2, 256, 0, stream>>>(csum, 2 * DH);
        k_colstats<<<200, 256, 0, stream>>>(T1f, csum, csq);
        k_normtanh<<<N_NODES, 256, 0, stream>>>(T1f, Tb, csum, csq, gamma + ch * DH,
                                                beta + ch * DH);
        // z_ch = zt @ Wg2.T + bg2 -> Zb (bf16), then gather into S,P
        gemm_b(5, Tb, Wg2_b + (size_t)ch * DH * DH, bg2 + ch * DH, Zb, nullptr, nullptr,
               N_NODES, DH, DH, stream);
        k_gather_ch<<<NB, 256, 0, stream>>>(edge_index, edge_id, Zb, S_b, P_b,
                                            D_INN + ch * DH);
    }

    // stage C (bf16 MFMA throughout; buffer reuse: GI->S_b, g->P_b, h1->G_b)
    gemm_b(2, S_b, Wgate_b, bgate, G_b, nullptr, nullptr, NB, H3, H3, stream);    // gate
    gemm_b(4, P_b, Wint_b, bint, S_b, nullptr, G_b, NB, H3, H3, stream);          // gi
    gemm_b(5, S_b, Wout_b, bout, P_b, nullptr, nullptr, NB, H3, H3, stream);      // g
    gemm_b(3, P_b, Wf1_b, bf1, G_b, nullptr, nullptr, NB, 1152, H3, stream);      // h1
    gemm_b(6, G_b, Wf2_b, bf2, h2f, nullptr, nullptr, NB, 576, 1152, stream);     // h2 (f32)
    k_final<<<NB, 64, 0, stream>>>(h2f, Wf3, bf3, outp);
}

// Round 4
// 4016.360 us; speedup vs baseline: 4.3588x; 4.3588x over previous
//
#include <hip/hip_runtime.h>
#include <math.h>

#define N_NODES 20000
#define D_INN   512
#define DH      256
#define NCH     7
#define NE      320000
#define NE2     100000
#define NB      8192
#define H3      2304   // 512 + 7*256
#define MAXN    0.996f

typedef unsigned short u16;
typedef __attribute__((ext_vector_type(8))) short bf16x8;
typedef __attribute__((ext_vector_type(4))) float f32x4;

__device__ __forceinline__ u16 f2b(float f) {    // RNE f32 -> bf16 bits
    unsigned int x = __float_as_uint(f);
    unsigned int r = (x + 0x7fffu + ((x >> 16) & 1u)) >> 16;
    return (u16)r;
}
__device__ __forceinline__ float b2f(u16 u) {
    return __uint_as_float(((unsigned int)u) << 16);
}

__device__ __forceinline__ float artanh_f(float x) {
    x = fminf(fmaxf(x, -1.0f + 1e-7f), 1.0f - 1e-7f);
    return 0.5f * (log1pf(x) - log1pf(-x));
}

__device__ __forceinline__ float block_sum256(float v) {
    __shared__ float sred[4];
    #pragma unroll
    for (int off = 32; off > 0; off >>= 1) v += __shfl_down(v, off, 64);
    int lane = threadIdx.x & 63;
    int w = threadIdx.x >> 6;
    if (lane == 0) sred[w] = v;
    __syncthreads();
    float tot = sred[0] + sred[1] + sred[2] + sred[3];
    __syncthreads();
    return tot;
}

__global__ void k_zero(float* __restrict__ p, int n) {
    int i = blockIdx.x * 256 + threadIdx.x;
    if (i < n) p[i] = 0.0f;
}
__global__ void k_izero(int* __restrict__ p, int n) {
    int i = blockIdx.x * 256 + threadIdx.x;
    if (i < n) p[i] = 0;
}

// f32 -> bf16 convert, 4 elems/thread, grid-stride (n4 = n/4)
__global__ void k_f2b(const float* __restrict__ s, u16* __restrict__ d, int n4) {
    int i = blockIdx.x * 256 + threadIdx.x;
    int stride = gridDim.x * 256;
    for (; i < n4; i += stride) {
        float4 v = ((const float4*)s)[i];
        unsigned int lo = (unsigned int)f2b(v.x) | ((unsigned int)f2b(v.y) << 16);
        unsigned int hi = (unsigned int)f2b(v.z) | ((unsigned int)f2b(v.w) << 16);
        uint2 o; o.x = lo; o.y = hi;
        ((uint2*)d)[i] = o;
    }
}

// ===== CSR build =====
__global__ void k_hist(const int* __restrict__ dst, int* __restrict__ cnt, int ne) {
    int i = blockIdx.x * 256 + threadIdx.x;
    if (i < ne) atomicAdd(&cnt[dst[i]], 1);
}

// single block, 256 threads: exclusive scan cnt[0..N) -> rowptr[0..N], cursor copy
__global__ void k_scan(const int* __restrict__ cnt, int* __restrict__ rowptr,
                       int* __restrict__ cursor) {
    __shared__ int part[256];
    int t = threadIdx.x;
    const int CH = (N_NODES + 255) / 256;
    int beg = t * CH;
    int end = beg + CH; if (end > N_NODES) end = N_NODES;
    int s = 0;
    for (int i = beg; i < end; ++i) s += cnt[i];
    part[t] = s;
    __syncthreads();
    for (int off = 1; off < 256; off <<= 1) {
        int v = (t >= off) ? part[t - off] : 0;
        __syncthreads();
        part[t] += v;
        __syncthreads();
    }
    int run = (t == 0) ? 0 : part[t - 1];
    for (int i = beg; i < end; ++i) {
        rowptr[i] = run; cursor[i] = run; run += cnt[i];
    }
    if (t == 255) rowptr[N_NODES] = part[255];
}

__global__ void k_place_sv(const int* __restrict__ src, const int* __restrict__ dst,
                           const float* __restrict__ val, int* __restrict__ cursor,
                           int* __restrict__ psrc, float* __restrict__ pval, int ne) {
    int i = blockIdx.x * 256 + threadIdx.x;
    if (i < ne) {
        int d = dst[i];
        int pos = atomicAdd(&cursor[d], 1);
        psrc[pos] = src[i];
        pval[pos] = val[i];
    }
}

__global__ void k_place_s(const int* __restrict__ src, const int* __restrict__ dst,
                          int* __restrict__ cursor, int* __restrict__ psrc, int ne) {
    int i = blockIdx.x * 256 + threadIdx.x;
    if (i < ne) {
        int d = dst[i];
        int pos = atomicAdd(&cursor[d], 1);
        psrc[pos] = src[i];
    }
}

// x_hyp = proj(expmap0(f1)) -> bf16; clamped row norm -> xhn (f32)
__global__ void k_expmap_proj_in(const float* __restrict__ f1,
                                 u16* __restrict__ xhyp, float* __restrict__ xhn) {
    int r = blockIdx.x, t = threadIdx.x;
    const float* u = f1 + (size_t)r * D_INN;
    float v0 = u[t], v1 = u[t + 256];
    float ss = block_sum256(v0 * v0 + v1 * v1);
    float nraw = sqrtf(ss);
    float n = fmaxf(nraw, 1e-15f);
    float c = tanhf(n) / n;
    float ny = c * nraw;
    float np = fmaxf(ny, 1e-15f);
    float s = (np > MAXN) ? MAXN / np : 1.0f;
    float cs = c * s;
    u16* o = xhyp + (size_t)r * D_INN;
    o[t] = f2b(cs * v0);
    o[t + 256] = f2b(cs * v1);
    if (t == 0) xhn[r] = fminf(np, MAXN);
}

__global__ void k_hb(const float* __restrict__ b_hyp,
                     float* __restrict__ hb, float* __restrict__ hb2) {
    int i = blockIdx.x, t = threadIdx.x;
    float v = b_hyp[i * DH + t];
    float ss = block_sum256(v * v);
    float nraw = sqrtf(ss);
    float n = fmaxf(nraw, 1e-15f);
    float c = tanhf(n) / n;
    float ny = c * nraw;
    float np = fmaxf(ny, 1e-15f);
    float s = (np > MAXN) ? MAXN / np : 1.0f;
    float hv = c * s * v;
    hb[i * DH + t] = hv;
    float s2 = block_sum256(hv * hv);
    if (t == 0) hb2[i] = s2;
}

// in-place f32 on T1 row: mobius_matvec finalize -> proj -> mobius_add(hb) -> proj -> logmap0
__global__ void k_rowfuse1(float* __restrict__ T1, const float* __restrict__ xhn,
                           const float* __restrict__ hb, const float* __restrict__ hb2) {
    int r = blockIdx.x, t = threadIdx.x;
    float* row = T1 + (size_t)r * DH;
    float m = row[t];
    float ss = block_sum256(m * m);
    float mxn_raw = sqrtf(ss);
    float mxn = fmaxf(mxn_raw, 1e-15f);
    float xn = xhn[r];
    float tt = tanhf(mxn / xn * artanh_f(xn));
    float coef = tt / mxn;
    float res = coef * m;
    float nres = coef * mxn_raw;
    float np = fmaxf(nres, 1e-15f);
    float s1 = (np > MAXN) ? MAXN / np : 1.0f;
    res *= s1;
    float n1 = fminf(np, MAXN);
    float hbv = hb[t];
    float xy = block_sum256(res * hbv);
    float x2 = n1 * n1, y2 = hb2[0];
    float num = (1.0f + 2.0f * xy + y2) * res + (1.0f - x2) * hbv;
    float den = fmaxf(1.0f + 2.0f * xy + x2 * y2, 1e-15f);
    float o = num / den;
    float no2 = block_sum256(o * o);
    float nop = fmaxf(sqrtf(no2), 1e-15f);
    float s2 = (nop > MAXN) ? MAXN / nop : 1.0f;
    float p = o * s2;
    float n2 = fminf(nop, MAXN);
    row[t] = artanh_f(n2) / n2 * p;
}

// CSR gather of val*xt rows + fused rowfuse2 hyperbolic chain -> bf16 out
__global__ void k_gather_fuse2(const int* __restrict__ rowptr, const int* __restrict__ psrc,
                               const float* __restrict__ pval, const float* __restrict__ xt,
                               u16* __restrict__ out) {
    __shared__ int ssrc[256];
    __shared__ float sval[256];
    int n = blockIdx.x, t = threadIdx.x;
    int beg = rowptr[n], end = rowptr[n + 1];
    float acc = 0.0f;
    for (int base = beg; base < end; base += 256) {
        int cnt = end - base; if (cnt > 256) cnt = 256;
        __syncthreads();
        if (t < cnt) { ssrc[t] = psrc[base + t]; sval[t] = pval[base + t]; }
        __syncthreads();
        for (int i = 0; i < cnt; ++i)
            acc = fmaf(sval[i], xt[(size_t)ssrc[i] * DH + t], acc);
    }
    // rowfuse2: expmap0->proj->logmap0->relu->expmap0->proj->logmap0
    float ss = block_sum256(acc * acc);
    float nraw = sqrtf(ss);
    float n_ = fmaxf(nraw, 1e-15f);
    float c1 = tanhf(n_) / n_;
    float h = c1 * acc;
    float nh = c1 * nraw;
    float np1 = fmaxf(nh, 1e-15f);
    float s1 = (np1 > MAXN) ? MAXN / np1 : 1.0f;
    h *= s1;
    float n1 = fminf(np1, MAXN);
    float u = artanh_f(n1) / n1 * h;
    u = fmaxf(u, 0.0f);
    float ss2 = block_sum256(u * u);
    float n2raw = sqrtf(ss2);
    float n2 = fmaxf(n2raw, 1e-15f);
    float c3 = tanhf(n2) / n2;
    float e = c3 * u;
    float ne = c3 * n2raw;
    float np3 = fmaxf(ne, 1e-15f);
    float s3 = (np3 > MAXN) ? MAXN / np3 : 1.0f;
    e *= s3;
    float n3 = fminf(np3, MAXN);
    out[(size_t)n * DH + t] = f2b(artanh_f(n3) / n3 * e);
}

// agg[n] = d[n] + sum_{in-edges} d[src]; write bf16
__global__ void k_gather_add(const int* __restrict__ rowptr, const int* __restrict__ psrc,
                             const float* __restrict__ d, u16* __restrict__ out) {
    __shared__ int ssrc[256];
    int n = blockIdx.x, t = threadIdx.x;
    int beg = rowptr[n], end = rowptr[n + 1];
    float acc = d[(size_t)n * DH + t];
    for (int base = beg; base < end; base += 256) {
        int cnt = end - base; if (cnt > 256) cnt = 256;
        __syncthreads();
        if (t < cnt) ssrc[t] = psrc[base + t];
        __syncthreads();
        for (int i = 0; i < cnt; ++i)
            acc += d[(size_t)ssrc[i] * DH + t];
    }
    out[(size_t)n * DH + t] = f2b(acc);
}

__global__ void k_colstats(const float* __restrict__ z,
                           float* __restrict__ csum, float* __restrict__ csq) {
    int t = threadIdx.x;
    int r0 = blockIdx.x * 100;
    float s = 0.0f, q = 0.0f;
    for (int r = r0; r < r0 + 100; ++r) {
        float v = z[(size_t)r * DH + t];
        s += v;
        q += v * v;
    }
    atomicAdd(&csum[t], s);
    atomicAdd(&csq[t], q);
}

// batchnorm + tanh; writes bf16
__global__ void k_normtanh(const float* __restrict__ z, u16* __restrict__ out,
                           const float* __restrict__ csum, const float* __restrict__ csq,
                           const float* __restrict__ gamma, const float* __restrict__ beta) {
    int idx = blockIdx.x * 256 + threadIdx.x;
    int j = idx & 255;
    float mu = csum[j] * (1.0f / N_NODES);
    float var = csq[j] * (1.0f / N_NODES) - mu * mu;
    float inv = 1.0f / sqrtf(var + 1e-5f);
    float v = (z[idx] - mu) * inv * gamma[j] + beta[j];
    out[idx] = f2b(tanhf(v));
}

// f1 slice of S,P (cols 0..511)
__global__ void k_pair0(const int* __restrict__ ei, const int* __restrict__ eid,
                        const float* __restrict__ f1, u16* __restrict__ S,
                        u16* __restrict__ P) {
    int b = blockIdx.x, t = threadIdx.x;
    int e = eid[b];
    int n0 = ei[e], n1 = ei[NE2 + e];
    const float* xa = f1 + (size_t)n0 * D_INN;
    const float* xb = f1 + (size_t)n1 * D_INN;
    u16* so = S + (size_t)b * H3;
    u16* po = P + (size_t)b * H3;
    for (int j = t; j < D_INN; j += 256) {
        float a = xa[j], c = xb[j];
        so[j] = f2b(a + c);
        po[j] = f2b(a * c);
    }
}

// channel slice of S,P gathered from z_ch (bf16, 20000x256)
__global__ void k_gather_ch(const int* __restrict__ ei, const int* __restrict__ eid,
                            const u16* __restrict__ z, u16* __restrict__ S,
                            u16* __restrict__ P, int col0) {
    int b = blockIdx.x, j = threadIdx.x;
    int e = eid[b];
    int n0 = ei[e], n1 = ei[NE2 + e];
    float a = b2f(z[(size_t)n0 * DH + j]);
    float c = b2f(z[(size_t)n1 * DH + j]);
    S[(size_t)b * H3 + col0 + j] = f2b(a + c);
    P[(size_t)b * H3 + col0 + j] = f2b(a * c);
}

__global__ void k_final(const float* __restrict__ h2, const float* __restrict__ Wf3,
                        const float* __restrict__ bf3, float* __restrict__ out) {
    int r = blockIdx.x, t = threadIdx.x;
    const float* hr = h2 + (size_t)r * 576;
    float acc[7] = {0, 0, 0, 0, 0, 0, 0};
    for (int cb = t; cb < 576; cb += 64) {
        float h = hr[cb];
        #pragma unroll
        for (int o = 0; o < 7; ++o) acc[o] = fmaf(h, Wf3[o * 576 + cb], acc[o]);
    }
    #pragma unroll
    for (int o = 0; o < 7; ++o) {
        #pragma unroll
        for (int off = 32; off > 0; off >>= 1) acc[o] += __shfl_down(acc[o], off, 64);
    }
    if (t == 0) {
        #pragma unroll
        for (int o = 0; o < 7; ++o) out[(size_t)r * 7 + o] = acc[o] + bf3[o];
    }
}

// ===== bf16 MFMA GEMM: C[M,N] = A[M,K] @ W[N,K]^T (+bias), A/W bf16 row-major.
// 128x128 tile, BK=32, 256 thr (4 waves, 2x2), 16x16x32 MFMA, 4x4 frags/wave.
// EP: 0=f32, 2=sigmoid->bf16, 3=relu->bf16, 4=aux*relu->bf16, 5=bf16, 6=relu->f32
template <int EP>
__global__ __launch_bounds__(256, 2) void k_gemm_mfma(
    const u16* __restrict__ A, const u16* __restrict__ W,
    const float* __restrict__ bias, void* __restrict__ outv,
    void* __restrict__ out2v, const u16* __restrict__ aux,
    int M, int N, int K) {
    __shared__ short As[4096];   // 128x32 bf16
    __shared__ short Ws[4096];
    const int t = threadIdx.x;
    const int lane = t & 63;
    const int w = t >> 6;
    const int wr = w >> 1, wc = w & 1;
    const int row0 = blockIdx.y * 128, col0 = blockIdx.x * 128;
    f32x4 acc[4][4] = {};
    for (int k0 = 0; k0 < K; k0 += 32) {
        #pragma unroll
        for (int p = 0; p < 2; ++p) {
            int i = t + p * 256;               // 0..511
            int row = i >> 2, kc = i & 3;
            int gr = row0 + row; gr = (gr < M) ? gr : (M - 1);
            int gc = col0 + row; gc = (gc < N) ? gc : (N - 1);
            uint4 va = *(const uint4*)(A + (size_t)gr * K + k0 + kc * 8);
            uint4 vw = *(const uint4*)(W + (size_t)gc * K + k0 + kc * 8);
            int off = (row >> 4) * 512 + kc * 128 + (row & 15) * 8;  // shorts
            *(uint4*)(As + off) = va;
            *(uint4*)(Ws + off) = vw;
        }
        __syncthreads();
        bf16x8 af[4], bfr[4];
        #pragma unroll
        for (int m = 0; m < 4; ++m)
            af[m] = *(const bf16x8*)(As + (wr * 4 + m) * 512 + lane * 8);
        #pragma unroll
        for (int n = 0; n < 4; ++n)
            bfr[n] = *(const bf16x8*)(Ws + (wc * 4 + n) * 512 + lane * 8);
        #pragma unroll
        for (int m = 0; m < 4; ++m)
            #pragma unroll
            for (int n = 0; n < 4; ++n)
                acc[m][n] = __builtin_amdgcn_mfma_f32_16x16x32_bf16(af[m], bfr[n], acc[m][n], 0, 0, 0);
        __syncthreads();
    }
    const int cl = lane & 15, rh = (lane >> 4) * 4;
    #pragma unroll
    for (int m = 0; m < 4; ++m) {
        #pragma unroll
        for (int n = 0; n < 4; ++n) {
            int col = col0 + wc * 64 + n * 16 + cl;
            if (col >= N) continue;
            float bv = bias ? bias[col] : 0.0f;
            #pragma unroll
            for (int r = 0; r < 4; ++r) {
                int row = row0 + wr * 64 + m * 16 + rh + r;
                if (row >= M) continue;
                float v = acc[m][n][r] + bv;
                size_t idx = (size_t)row * N + col;
                if (EP == 0) ((float*)outv)[idx] = v;
                if (EP == 2) ((u16*)outv)[idx] = f2b(1.0f / (1.0f + expf(-v)));
                if (EP == 3) ((u16*)outv)[idx] = f2b(fmaxf(v, 0.0f));
                if (EP == 4) { float g = b2f(aux[idx]); ((u16*)outv)[idx] = f2b(g * fmaxf(v, 0.0f)); }
                if (EP == 5) ((u16*)outv)[idx] = f2b(v);
                if (EP == 6) ((float*)outv)[idx] = fmaxf(v, 0.0f);
            }
        }
    }
}

static inline void gemm_b(int ep, const u16* A, const u16* W, const float* bias, void* out,
                          void* out2, const u16* aux, int M, int N, int K, hipStream_t st) {
    dim3 g((N + 127) / 128, (M + 127) / 128);
    switch (ep) {
        case 0: k_gemm_mfma<0><<<g, 256, 0, st>>>(A, W, bias, out, out2, aux, M, N, K); break;
        case 2: k_gemm_mfma<2><<<g, 256, 0, st>>>(A, W, bias, out, out2, aux, M, N, K); break;
        case 3: k_gemm_mfma<3><<<g, 256, 0, st>>>(A, W, bias, out, out2, aux, M, N, K); break;
        case 4: k_gemm_mfma<4><<<g, 256, 0, st>>>(A, W, bias, out, out2, aux, M, N, K); break;
        case 5: k_gemm_mfma<5><<<g, 256, 0, st>>>(A, W, bias, out, out2, aux, M, N, K); break;
        case 6: k_gemm_mfma<6><<<g, 256, 0, st>>>(A, W, bias, out, out2, aux, M, N, K); break;
    }
}

static inline void conv_w(const float* s, u16* d, size_t n, hipStream_t st) {
    int n4 = (int)(n / 4);
    int grid = (n4 + 255) / 256;
    if (grid > 2048) grid = 2048;
    k_f2b<<<grid, 256, 0, st>>>(s, d, n4);
}

extern "C" void kernel_launch(void* const* d_in, const int* in_sizes, int n_in, void* d_out,
                              int out_size, void* d_ws, size_t ws_size, hipStream_t stream) {
    const float* f1 = (const float*)d_in[0];
    const int* adj_src = (const int*)d_in[1];
    const int* adj_dst = (const int*)d_in[2];
    const float* adj_val = (const float*)d_in[3];
    const int* edge_src = (const int*)d_in[4];
    const int* edge_dst = (const int*)d_in[5];
    const int* edge_index = (const int*)d_in[6];
    const int* edge_id = (const int*)d_in[7];
    const float* W_hyp = (const float*)d_in[8];
    const float* b_hyp = (const float*)d_in[9];
    const float* Wd = (const float*)d_in[10];
    const float* bd = (const float*)d_in[11];
    const float* Wg1 = (const float*)d_in[12];
    const float* bg1 = (const float*)d_in[13];
    const float* gamma = (const float*)d_in[14];
    const float* beta = (const float*)d_in[15];
    const float* Wg2 = (const float*)d_in[16];
    const float* bg2 = (const float*)d_in[17];
    const float* Wgate = (const float*)d_in[18];
    const float* bgate = (const float*)d_in[19];
    const float* Wint = (const float*)d_in[20];
    const float* bint = (const float*)d_in[21];
    const float* Wout = (const float*)d_in[22];
    const float* bout = (const float*)d_in[23];
    const float* Wf1 = (const float*)d_in[24];
    const float* bf1 = (const float*)d_in[25];
    const float* Wf2 = (const float*)d_in[26];
    const float* bf2 = (const float*)d_in[27];
    const float* Wf3 = (const float*)d_in[28];
    const float* bf3 = (const float*)d_in[29];
    float* outp = (float*)d_out;

    // ---- workspace bump allocator (~215 MB) ----
    char* base = (char*)d_ws;
    size_t off = 0;
    auto alloc = [&](size_t bytes) -> char* {
        char* p = base + off;
        off += (bytes + 255) & ~(size_t)255;
        return p;
    };
    u16* Whyp_b = (u16*)alloc((size_t)NCH * DH * D_INN * 2);
    u16* Wd_b   = (u16*)alloc((size_t)NCH * DH * DH * 2);
    u16* Wg1_b  = (u16*)alloc((size_t)NCH * DH * DH * 2);
    u16* Wg2_b  = (u16*)alloc((size_t)NCH * DH * DH * 2);
    u16* Wgate_b = (u16*)alloc((size_t)H3 * H3 * 2);
    u16* Wint_b  = (u16*)alloc((size_t)H3 * H3 * 2);
    u16* Wout_b  = (u16*)alloc((size_t)H3 * H3 * 2);
    u16* Wf1_b   = (u16*)alloc((size_t)1152 * H3 * 2);
    u16* Wf2_b   = (u16*)alloc((size_t)576 * 1152 * 2);
    u16* S_b = (u16*)alloc((size_t)NB * H3 * 2);
    u16* P_b = (u16*)alloc((size_t)NB * H3 * 2);
    u16* G_b = (u16*)alloc((size_t)NB * H3 * 2);       // gate; later h1 (8192x1152)
    u16* xhyp_b = (u16*)alloc((size_t)N_NODES * D_INN * 2);   // stage C: h2f overlays
    float* T1f = (float*)alloc((size_t)N_NODES * DH * 4);
    u16* Tb = (u16*)alloc((size_t)N_NODES * DH * 2);
    u16* Zb = (u16*)alloc((size_t)N_NODES * DH * 2);
    // CSR scratch
    int* cnt = (int*)alloc((size_t)N_NODES * 4);
    int* rowptr = (int*)alloc((size_t)(N_NODES + 1) * 4);
    int* cursor = (int*)alloc((size_t)N_NODES * 4);
    int* psrc = (int*)alloc((size_t)NE * 4);
    float* pval = (float*)alloc((size_t)NE * 4);
    float* xhn = (float*)alloc((size_t)N_NODES * 4);
    float* hb = (float*)alloc((size_t)NCH * DH * 4);
    float* hb2 = (float*)alloc(NCH * 4);
    float* csum = (float*)alloc(DH * 4);
    float* csq = (float*)alloc(DH * 4);
    float* h2f = (float*)xhyp_b;   // 8192x576 f32 = 18.87MB <= 20.48MB (xhyp dead in stage C)

    const int EG = (NE + 255) / 256;   // 1250 blocks for edge-sized kernels

    // weight conversions (once per launch)
    conv_w(W_hyp, Whyp_b, (size_t)NCH * DH * D_INN, stream);
    conv_w(Wd, Wd_b, (size_t)NCH * DH * DH, stream);
    conv_w(Wg1, Wg1_b, (size_t)NCH * DH * DH, stream);
    conv_w(Wg2, Wg2_b, (size_t)NCH * DH * DH, stream);
    conv_w(Wgate, Wgate_b, (size_t)H3 * H3, stream);
    conv_w(Wint, Wint_b, (size_t)H3 * H3, stream);
    conv_w(Wout, Wout_b, (size_t)H3 * H3, stream);
    conv_w(Wf1, Wf1_b, (size_t)1152 * H3, stream);
    conv_w(Wf2, Wf2_b, (size_t)576 * 1152, stream);

    k_expmap_proj_in<<<N_NODES, 256, 0, stream>>>(f1, xhyp_b, xhn);
    k_hb<<<NCH, 256, 0, stream>>>(b_hyp, hb, hb2);
    k_pair0<<<NB, 256, 0, stream>>>(edge_index, edge_id, f1, S_b, P_b);

    for (int ch = 0; ch < NCH; ++ch) {
        const int* asrc = adj_src + (size_t)ch * NE;
        const int* adst = adj_dst + (size_t)ch * NE;
        const float* aval = adj_val + (size_t)ch * NE;
        const int* esrc = edge_src + (size_t)ch * NE;
        const int* edst = edge_dst + (size_t)ch * NE;

        // mx = x_hyp @ W_hyp[ch].T  -> T1f (f32)
        gemm_b(0, xhyp_b, Whyp_b + (size_t)ch * DH * D_INN, nullptr, T1f, nullptr, nullptr,
               N_NODES, DH, D_INN, stream);
        k_rowfuse1<<<N_NODES, 256, 0, stream>>>(T1f, xhn, hb + ch * DH, hb2 + ch);

        // support = segsum(val * xt[src], dst)  via CSR gather, fused rowfuse2 -> Tb (bf16)
        k_izero<<<(N_NODES + 255) / 256, 256, 0, stream>>>(cnt, N_NODES);
        k_hist<<<EG, 256, 0, stream>>>(adst, cnt, NE);
        k_scan<<<1, 256, 0, stream>>>(cnt, rowptr, cursor);
        k_place_sv<<<EG, 256, 0, stream>>>(asrc, adst, aval, cursor, psrc, pval, NE);
        k_gather_fuse2<<<N_NODES, 256, 0, stream>>>(rowptr, psrc, pval, T1f, Tb);

        // d = u @ Wd.T + bd -> T1f (f32)
        gemm_b(0, Tb, Wd_b + (size_t)ch * DH * DH, bd + ch * DH, T1f, nullptr, nullptr,
               N_NODES, DH, DH, stream);

        // agg = d + segsum(d[esrc], edst) via CSR gather -> Tb (bf16)
        k_izero<<<(N_NODES + 255) / 256, 256, 0, stream>>>(cnt, N_NODES);
        k_hist<<<EG, 256, 0, stream>>>(edst, cnt, NE);
        k_scan<<<1, 256, 0, stream>>>(cnt, rowptr, cursor);
        k_place_s<<<EG, 256, 0, stream>>>(esrc, edst, cursor, psrc, NE);
        k_gather_add<<<N_NODES, 256, 0, stream>>>(rowptr, psrc, T1f, Tb);

        // z = agg @ Wg1.T + bg1 -> T1f (f32)
        gemm_b(0, Tb, Wg1_b + (size_t)ch * DH * DH, bg1 + ch * DH, T1f, nullptr, nullptr,
               N_NODES, DH, DH, stream);
        k_zero<<<2, 256, 0, stream>>>(csum, 2 * DH);
        k_colstats<<<200, 256, 0, stream>>>(T1f, csum, csq);
        k_normtanh<<<N_NODES, 256, 0, stream>>>(T1f, Tb, csum, csq, gamma + ch * DH,
                                                beta + ch * DH);
        // z_ch = zt @ Wg2.T + bg2 -> Zb (bf16), then gather into S,P
        gemm_b(5, Tb, Wg2_b + (size_t)ch * DH * DH, bg2 + ch * DH, Zb, nullptr, nullptr,
               N_NODES, DH, DH, stream);
        k_gather_ch<<<NB, 256, 0, stream>>>(edge_index, edge_id, Zb, S_b, P_b,
                                            D_INN + ch * DH);
    }

    // stage C (bf16 MFMA; buffer reuse: gi->S_b, g->P_b, h1->G_b)
    gemm_b(2, S_b, Wgate_b, bgate, G_b, nullptr, nullptr, NB, H3, H3, stream);    // gate
    gemm_b(4, P_b, Wint_b, bint, S_b, nullptr, G_b, NB, H3, H3, stream);          // gi
    gemm_b(5, S_b, Wout_b, bout, P_b, nullptr, nullptr, NB, H3, H3, stream);      // g
    gemm_b(3, P_b, Wf1_b, bf1, G_b, nullptr, nullptr, NB, 1152, H3, stream);      // h1
    gemm_b(6, G_b, Wf2_b, bf2, h2f, nullptr, nullptr, NB, 576, 1152, stream);     // h2 (f32)
    k_final<<<NB, 64, 0, stream>>>(h2f, Wf3, bf3, outp);
}

// Round 5
// 2944.717 us; speedup vs baseline: 5.9451x; 1.3639x over previous
//
#include <hip/hip_runtime.h>
#include <math.h>

#define N_NODES 20000
#define D_INN   512
#define DH      256
#define NCH     7
#define NE      320000
#define NE2     100000
#define NB      8192
#define H3      2304   // 512 + 7*256
#define MAXN    0.996f

typedef unsigned short u16;
typedef __attribute__((ext_vector_type(8))) short bf16x8;
typedef __attribute__((ext_vector_type(4))) float f32x4;

__device__ __forceinline__ u16 f2b(float f) {    // RNE f32 -> bf16 bits
    unsigned int x = __float_as_uint(f);
    unsigned int r = (x + 0x7fffu + ((x >> 16) & 1u)) >> 16;
    return (u16)r;
}
__device__ __forceinline__ float b2f(u16 u) {
    return __uint_as_float(((unsigned int)u) << 16);
}

__device__ __forceinline__ float artanh_f(float x) {
    x = fminf(fmaxf(x, -1.0f + 1e-7f), 1.0f - 1e-7f);
    return 0.5f * (log1pf(x) - log1pf(-x));
}

__device__ __forceinline__ float block_sum256(float v) {
    __shared__ float sred[4];
    #pragma unroll
    for (int off = 32; off > 0; off >>= 1) v += __shfl_down(v, off, 64);
    int lane = threadIdx.x & 63;
    int w = threadIdx.x >> 6;
    if (lane == 0) sred[w] = v;
    __syncthreads();
    float tot = sred[0] + sred[1] + sred[2] + sred[3];
    __syncthreads();
    return tot;
}

__global__ void k_zero(float* __restrict__ p, int n) {
    int i = blockIdx.x * 256 + threadIdx.x;
    if (i < n) p[i] = 0.0f;
}
__global__ void k_izero(int* __restrict__ p, int n) {
    int i = blockIdx.x * 256 + threadIdx.x;
    if (i < n) p[i] = 0;
}

__global__ void k_f2b(const float* __restrict__ s, u16* __restrict__ d, int n4) {
    int i = blockIdx.x * 256 + threadIdx.x;
    int stride = gridDim.x * 256;
    for (; i < n4; i += stride) {
        float4 v = ((const float4*)s)[i];
        unsigned int lo = (unsigned int)f2b(v.x) | ((unsigned int)f2b(v.y) << 16);
        unsigned int hi = (unsigned int)f2b(v.z) | ((unsigned int)f2b(v.w) << 16);
        uint2 o; o.x = lo; o.y = hi;
        ((uint2*)d)[i] = o;
    }
}

// ===== batched CSR build (blockIdx.y = channel-in-group) =====
__global__ void k_hist(const int* __restrict__ dst, int* __restrict__ cnt, int ne) {
    int z = blockIdx.y;
    dst += (size_t)z * ne;
    cnt += (size_t)z * N_NODES;
    int i = blockIdx.x * 256 + threadIdx.x;
    if (i < ne) atomicAdd(&cnt[dst[i]], 1);
}

// one block per channel: exclusive scan cnt -> rowptr + cursor copy
__global__ void k_scan(const int* __restrict__ cnt, int* __restrict__ rowptr,
                       int* __restrict__ cursor) {
    int z = blockIdx.x;
    cnt += (size_t)z * N_NODES;
    rowptr += (size_t)z * (N_NODES + 1);
    cursor += (size_t)z * N_NODES;
    __shared__ int part[256];
    int t = threadIdx.x;
    const int CH = (N_NODES + 255) / 256;
    int beg = t * CH;
    int end = beg + CH; if (end > N_NODES) end = N_NODES;
    int s = 0;
    for (int i = beg; i < end; ++i) s += cnt[i];
    part[t] = s;
    __syncthreads();
    for (int off = 1; off < 256; off <<= 1) {
        int v = (t >= off) ? part[t - off] : 0;
        __syncthreads();
        part[t] += v;
        __syncthreads();
    }
    int run = (t == 0) ? 0 : part[t - 1];
    for (int i = beg; i < end; ++i) {
        rowptr[i] = run; cursor[i] = run; run += cnt[i];
    }
    if (t == 255) rowptr[N_NODES] = part[255];
}

__global__ void k_place_sv(const int* __restrict__ src, const int* __restrict__ dst,
                           const float* __restrict__ val, int* __restrict__ cursor,
                           int* __restrict__ psrc, float* __restrict__ pval, int ne) {
    int z = blockIdx.y;
    src += (size_t)z * ne; dst += (size_t)z * ne; val += (size_t)z * ne;
    cursor += (size_t)z * N_NODES; psrc += (size_t)z * ne; pval += (size_t)z * ne;
    int i = blockIdx.x * 256 + threadIdx.x;
    if (i < ne) {
        int d = dst[i];
        int pos = atomicAdd(&cursor[d], 1);
        psrc[pos] = src[i];
        pval[pos] = val[i];
    }
}

__global__ void k_place_s(const int* __restrict__ src, const int* __restrict__ dst,
                          int* __restrict__ cursor, int* __restrict__ psrc, int ne) {
    int z = blockIdx.y;
    src += (size_t)z * ne; dst += (size_t)z * ne;
    cursor += (size_t)z * N_NODES; psrc += (size_t)z * ne;
    int i = blockIdx.x * 256 + threadIdx.x;
    if (i < ne) {
        int d = dst[i];
        int pos = atomicAdd(&cursor[d], 1);
        psrc[pos] = src[i];
    }
}

// x_hyp = proj(expmap0(f1)) -> bf16; clamped row norm -> xhn (f32)
__global__ void k_expmap_proj_in(const float* __restrict__ f1,
                                 u16* __restrict__ xhyp, float* __restrict__ xhn) {
    int r = blockIdx.x, t = threadIdx.x;
    const float* u = f1 + (size_t)r * D_INN;
    float v0 = u[t], v1 = u[t + 256];
    float ss = block_sum256(v0 * v0 + v1 * v1);
    float nraw = sqrtf(ss);
    float n = fmaxf(nraw, 1e-15f);
    float c = tanhf(n) / n;
    float ny = c * nraw;
    float np = fmaxf(ny, 1e-15f);
    float s = (np > MAXN) ? MAXN / np : 1.0f;
    float cs = c * s;
    u16* o = xhyp + (size_t)r * D_INN;
    o[t] = f2b(cs * v0);
    o[t + 256] = f2b(cs * v1);
    if (t == 0) xhn[r] = fminf(np, MAXN);
}

__global__ void k_hb(const float* __restrict__ b_hyp,
                     float* __restrict__ hb, float* __restrict__ hb2) {
    int i = blockIdx.x, t = threadIdx.x;
    float v = b_hyp[i * DH + t];
    float ss = block_sum256(v * v);
    float nraw = sqrtf(ss);
    float n = fmaxf(nraw, 1e-15f);
    float c = tanhf(n) / n;
    float ny = c * nraw;
    float np = fmaxf(ny, 1e-15f);
    float s = (np > MAXN) ? MAXN / np : 1.0f;
    float hv = c * s * v;
    hb[i * DH + t] = hv;
    float s2 = block_sum256(hv * hv);
    if (t == 0) hb2[i] = s2;
}

// batched (blockIdx.y = z); in-place bf16 row: mobius finalize->proj->mobius_add->proj->logmap0
__global__ void k_rowfuse1(u16* __restrict__ T, const float* __restrict__ xhn,
                           const float* __restrict__ hb, const float* __restrict__ hb2) {
    int z = blockIdx.y;
    u16* row = T + ((size_t)z * N_NODES + blockIdx.x) * DH;
    hb += (size_t)z * DH;
    int t = threadIdx.x;
    float m = b2f(row[t]);
    float ss = block_sum256(m * m);
    float mxn_raw = sqrtf(ss);
    float mxn = fmaxf(mxn_raw, 1e-15f);
    float xn = xhn[blockIdx.x];
    float tt = tanhf(mxn / xn * artanh_f(xn));
    float coef = tt / mxn;
    float res = coef * m;
    float nres = coef * mxn_raw;
    float np = fmaxf(nres, 1e-15f);
    float s1 = (np > MAXN) ? MAXN / np : 1.0f;
    res *= s1;
    float n1 = fminf(np, MAXN);
    float hbv = hb[t];
    float xy = block_sum256(res * hbv);
    float x2 = n1 * n1, y2 = hb2[z];
    float num = (1.0f + 2.0f * xy + y2) * res + (1.0f - x2) * hbv;
    float den = fmaxf(1.0f + 2.0f * xy + x2 * y2, 1e-15f);
    float o = num / den;
    float no2 = block_sum256(o * o);
    float nop = fmaxf(sqrtf(no2), 1e-15f);
    float s2 = (nop > MAXN) ? MAXN / nop : 1.0f;
    float p = o * s2;
    float n2 = fminf(nop, MAXN);
    row[t] = f2b(artanh_f(n2) / n2 * p);
}

// batched CSR gather of val*xt rows + fused rowfuse2 chain -> bf16 out
__global__ void k_gather_fuse2(const int* __restrict__ rowptr, const int* __restrict__ psrc,
                               const float* __restrict__ pval, const u16* __restrict__ xt,
                               u16* __restrict__ out) {
    int z = blockIdx.y;
    rowptr += (size_t)z * (N_NODES + 1);
    psrc += (size_t)z * NE;
    pval += (size_t)z * NE;
    xt += (size_t)z * N_NODES * DH;
    out += (size_t)z * N_NODES * DH;
    __shared__ int ssrc[256];
    __shared__ float sval[256];
    int n = blockIdx.x, t = threadIdx.x;
    int beg = rowptr[n], end = rowptr[n + 1];
    float acc = 0.0f;
    for (int base = beg; base < end; base += 256) {
        int cnt = end - base; if (cnt > 256) cnt = 256;
        __syncthreads();
        if (t < cnt) { ssrc[t] = psrc[base + t]; sval[t] = pval[base + t]; }
        __syncthreads();
        for (int i = 0; i < cnt; ++i)
            acc = fmaf(sval[i], b2f(xt[(size_t)ssrc[i] * DH + t]), acc);
    }
    float ss = block_sum256(acc * acc);
    float nraw = sqrtf(ss);
    float n_ = fmaxf(nraw, 1e-15f);
    float c1 = tanhf(n_) / n_;
    float h = c1 * acc;
    float nh = c1 * nraw;
    float np1 = fmaxf(nh, 1e-15f);
    float s1 = (np1 > MAXN) ? MAXN / np1 : 1.0f;
    h *= s1;
    float n1 = fminf(np1, MAXN);
    float u = artanh_f(n1) / n1 * h;
    u = fmaxf(u, 0.0f);
    float ss2 = block_sum256(u * u);
    float n2raw = sqrtf(ss2);
    float n2 = fmaxf(n2raw, 1e-15f);
    float c3 = tanhf(n2) / n2;
    float e = c3 * u;
    float ne = c3 * n2raw;
    float np3 = fmaxf(ne, 1e-15f);
    float s3 = (np3 > MAXN) ? MAXN / np3 : 1.0f;
    e *= s3;
    float n3 = fminf(np3, MAXN);
    out[(size_t)n * DH + t] = f2b(artanh_f(n3) / n3 * e);
}

// batched: agg[n] = d[n] + sum_in d[src]; bf16 in/out
__global__ void k_gather_add(const int* __restrict__ rowptr, const int* __restrict__ psrc,
                             const u16* __restrict__ d, u16* __restrict__ out) {
    int z = blockIdx.y;
    rowptr += (size_t)z * (N_NODES + 1);
    psrc += (size_t)z * NE;
    d += (size_t)z * N_NODES * DH;
    out += (size_t)z * N_NODES * DH;
    __shared__ int ssrc[256];
    int n = blockIdx.x, t = threadIdx.x;
    int beg = rowptr[n], end = rowptr[n + 1];
    float acc = b2f(d[(size_t)n * DH + t]);
    for (int base = beg; base < end; base += 256) {
        int cnt = end - base; if (cnt > 256) cnt = 256;
        __syncthreads();
        if (t < cnt) ssrc[t] = psrc[base + t];
        __syncthreads();
        for (int i = 0; i < cnt; ++i)
            acc += b2f(d[(size_t)ssrc[i] * DH + t]);
    }
    out[(size_t)n * DH + t] = f2b(acc);
}

// batched column stats from bf16
__global__ void k_colstats(const u16* __restrict__ zp,
                           float* __restrict__ csum, float* __restrict__ csq) {
    int z = blockIdx.y;
    zp += (size_t)z * N_NODES * DH;
    csum += (size_t)z * DH;
    csq += (size_t)z * DH;
    int t = threadIdx.x;
    int r0 = blockIdx.x * 100;
    float s = 0.0f, q = 0.0f;
    for (int r = r0; r < r0 + 100; ++r) {
        float v = b2f(zp[(size_t)r * DH + t]);
        s += v;
        q += v * v;
    }
    atomicAdd(&csum[t], s);
    atomicAdd(&csq[t], q);
}

// batched batchnorm + tanh, in-place bf16
__global__ void k_normtanh(u16* __restrict__ zp, const float* __restrict__ csum,
                           const float* __restrict__ csq, const float* __restrict__ gamma,
                           const float* __restrict__ beta) {
    int z = blockIdx.y;
    u16* row = zp + ((size_t)z * N_NODES + blockIdx.x) * DH;
    csum += (size_t)z * DH; csq += (size_t)z * DH;
    gamma += (size_t)z * DH; beta += (size_t)z * DH;
    int j = threadIdx.x;
    float mu = csum[j] * (1.0f / N_NODES);
    float var = csq[j] * (1.0f / N_NODES) - mu * mu;
    float inv = 1.0f / sqrtf(var + 1e-5f);
    float v = (b2f(row[j]) - mu) * inv * gamma[j] + beta[j];
    row[j] = f2b(tanhf(v));
}

// f1 slice of S,P (cols 0..511)
__global__ void k_pair0(const int* __restrict__ ei, const int* __restrict__ eid,
                        const float* __restrict__ f1, u16* __restrict__ S,
                        u16* __restrict__ P) {
    int b = blockIdx.x, t = threadIdx.x;
    int e = eid[b];
    int n0 = ei[e], n1 = ei[NE2 + e];
    const float* xa = f1 + (size_t)n0 * D_INN;
    const float* xb = f1 + (size_t)n1 * D_INN;
    u16* so = S + (size_t)b * H3;
    u16* po = P + (size_t)b * H3;
    for (int j = t; j < D_INN; j += 256) {
        float a = xa[j], c = xb[j];
        so[j] = f2b(a + c);
        po[j] = f2b(a * c);
    }
}

// batched channel slice of S,P gathered from z_ch (bf16)
__global__ void k_gather_ch(const int* __restrict__ ei, const int* __restrict__ eid,
                            const u16* __restrict__ zch, u16* __restrict__ S,
                            u16* __restrict__ P, int col0base) {
    int z = blockIdx.y;
    const u16* zp = zch + (size_t)z * N_NODES * DH;
    int col0 = col0base + z * DH;
    int b = blockIdx.x, j = threadIdx.x;
    int e = eid[b];
    int n0 = ei[e], n1 = ei[NE2 + e];
    float a = b2f(zp[(size_t)n0 * DH + j]);
    float c = b2f(zp[(size_t)n1 * DH + j]);
    S[(size_t)b * H3 + col0 + j] = f2b(a + c);
    P[(size_t)b * H3 + col0 + j] = f2b(a * c);
}

__global__ void k_final(const float* __restrict__ h2, const float* __restrict__ Wf3,
                        const float* __restrict__ bf3, float* __restrict__ out) {
    int r = blockIdx.x, t = threadIdx.x;
    const float* hr = h2 + (size_t)r * 576;
    float acc[7] = {0, 0, 0, 0, 0, 0, 0};
    for (int cb = t; cb < 576; cb += 64) {
        float h = hr[cb];
        #pragma unroll
        for (int o = 0; o < 7; ++o) acc[o] = fmaf(h, Wf3[o * 576 + cb], acc[o]);
    }
    #pragma unroll
    for (int o = 0; o < 7; ++o) {
        #pragma unroll
        for (int off = 32; off > 0; off >>= 1) acc[o] += __shfl_down(acc[o], off, 64);
    }
    if (t == 0) {
        #pragma unroll
        for (int o = 0; o < 7; ++o) out[(size_t)r * 7 + o] = acc[o] + bf3[o];
    }
}

// ===== bf16 MFMA GEMM (batched over blockIdx.z with strides).
// C[z][M,N] = A[z][M,K] @ W[z][N,K]^T + bias[z]; 128x128 tile, BK=32, 4 waves.
// LDS 16B-slot swizzle s = kc*16 + ((r + 2*kc)&15) on write AND frag read
// (breaks kc bank collision: 4-way -> 2-way = free).
// EP: 2=sigmoid->bf16, 3=relu->bf16, 4=aux*relu->bf16, 5=bf16, 6=relu->f32
template <int EP>
__global__ __launch_bounds__(256, 2) void k_gemm_mfma(
    const u16* __restrict__ A, const u16* __restrict__ W,
    const float* __restrict__ bias, void* __restrict__ outv,
    const u16* __restrict__ aux, int M, int N, int K,
    size_t sA, size_t sW, size_t sC, int sBias) {
    __shared__ short As[4096];   // 128x32 bf16
    __shared__ short Ws[4096];
    const int z = blockIdx.z;
    A += (size_t)z * sA;
    W += (size_t)z * sW;
    const size_t zC = (size_t)z * sC;
    const int t = threadIdx.x;
    const int lane = t & 63;
    const int w = t >> 6;
    const int wr = w >> 1, wc = w & 1;
    const int row0 = blockIdx.y * 128, col0 = blockIdx.x * 128;
    const int rkc = lane >> 4, rr = lane & 15;
    const int rdoff = (rkc * 16 + ((rr + 2 * rkc) & 15)) * 8;  // shorts
    f32x4 acc[4][4] = {};
    for (int k0 = 0; k0 < K; k0 += 32) {
        #pragma unroll
        for (int p = 0; p < 2; ++p) {
            int i = t + p * 256;               // 0..511
            int row = i >> 2, kc = i & 3;
            int gr = row0 + row; gr = (gr < M) ? gr : (M - 1);
            int gc = col0 + row; gc = (gc < N) ? gc : (N - 1);
            uint4 va = *(const uint4*)(A + (size_t)gr * K + k0 + kc * 8);
            uint4 vw = *(const uint4*)(W + (size_t)gc * K + k0 + kc * 8);
            int off = (row >> 4) * 512 + (kc * 16 + (((row & 15) + 2 * kc) & 15)) * 8;
            *(uint4*)(As + off) = va;
            *(uint4*)(Ws + off) = vw;
        }
        __syncthreads();
        bf16x8 af[4], bfr[4];
        #pragma unroll
        for (int m = 0; m < 4; ++m)
            af[m] = *(const bf16x8*)(As + (wr * 4 + m) * 512 + rdoff);
        #pragma unroll
        for (int n = 0; n < 4; ++n)
            bfr[n] = *(const bf16x8*)(Ws + (wc * 4 + n) * 512 + rdoff);
        #pragma unroll
        for (int m = 0; m < 4; ++m)
            #pragma unroll
            for (int n = 0; n < 4; ++n)
                acc[m][n] = __builtin_amdgcn_mfma_f32_16x16x32_bf16(af[m], bfr[n], acc[m][n], 0, 0, 0);
        __syncthreads();
    }
    const int cl = lane & 15, rh = (lane >> 4) * 4;
    #pragma unroll
    for (int m = 0; m < 4; ++m) {
        #pragma unroll
        for (int n = 0; n < 4; ++n) {
            int col = col0 + wc * 64 + n * 16 + cl;
            if (col >= N) continue;
            float bv = bias ? bias[z * sBias + col] : 0.0f;
            #pragma unroll
            for (int r = 0; r < 4; ++r) {
                int row = row0 + wr * 64 + m * 16 + rh + r;
                if (row >= M) continue;
                float v = acc[m][n][r] + bv;
                size_t idx = zC + (size_t)row * N + col;
                if (EP == 2) ((u16*)outv)[idx] = f2b(1.0f / (1.0f + expf(-v)));
                if (EP == 3) ((u16*)outv)[idx] = f2b(fmaxf(v, 0.0f));
                if (EP == 4) { float g = b2f(aux[idx]); ((u16*)outv)[idx] = f2b(g * fmaxf(v, 0.0f)); }
                if (EP == 5) ((u16*)outv)[idx] = f2b(v);
                if (EP == 6) ((float*)outv)[idx] = fmaxf(v, 0.0f);
            }
        }
    }
}

static inline void gemm_b(int ep, const u16* A, const u16* W, const float* bias, void* out,
                          const u16* aux, int M, int N, int K, int Z,
                          size_t sA, size_t sW, size_t sC, int sBias, hipStream_t st) {
    dim3 g((N + 127) / 128, (M + 127) / 128, Z);
    switch (ep) {
        case 2: k_gemm_mfma<2><<<g, 256, 0, st>>>(A, W, bias, out, aux, M, N, K, sA, sW, sC, sBias); break;
        case 3: k_gemm_mfma<3><<<g, 256, 0, st>>>(A, W, bias, out, aux, M, N, K, sA, sW, sC, sBias); break;
        case 4: k_gemm_mfma<4><<<g, 256, 0, st>>>(A, W, bias, out, aux, M, N, K, sA, sW, sC, sBias); break;
        case 5: k_gemm_mfma<5><<<g, 256, 0, st>>>(A, W, bias, out, aux, M, N, K, sA, sW, sC, sBias); break;
        case 6: k_gemm_mfma<6><<<g, 256, 0, st>>>(A, W, bias, out, aux, M, N, K, sA, sW, sC, sBias); break;
    }
}

static inline void conv_w(const float* s, u16* d, size_t n, hipStream_t st) {
    int n4 = (int)(n / 4);
    int grid = (n4 + 255) / 256;
    if (grid > 2048) grid = 2048;
    k_f2b<<<grid, 256, 0, st>>>(s, d, n4);
}

extern "C" void kernel_launch(void* const* d_in, const int* in_sizes, int n_in, void* d_out,
                              int out_size, void* d_ws, size_t ws_size, hipStream_t stream) {
    const float* f1 = (const float*)d_in[0];
    const int* adj_src = (const int*)d_in[1];
    const int* adj_dst = (const int*)d_in[2];
    const float* adj_val = (const float*)d_in[3];
    const int* edge_src = (const int*)d_in[4];
    const int* edge_dst = (const int*)d_in[5];
    const int* edge_index = (const int*)d_in[6];
    const int* edge_id = (const int*)d_in[7];
    const float* W_hyp = (const float*)d_in[8];
    const float* b_hyp = (const float*)d_in[9];
    const float* Wd = (const float*)d_in[10];
    const float* bd = (const float*)d_in[11];
    const float* Wg1 = (const float*)d_in[12];
    const float* bg1 = (const float*)d_in[13];
    const float* gamma = (const float*)d_in[14];
    const float* beta = (const float*)d_in[15];
    const float* Wg2 = (const float*)d_in[16];
    const float* bg2 = (const float*)d_in[17];
    const float* Wgate = (const float*)d_in[18];
    const float* bgate = (const float*)d_in[19];
    const float* Wint = (const float*)d_in[20];
    const float* bint = (const float*)d_in[21];
    const float* Wout = (const float*)d_in[22];
    const float* bout = (const float*)d_in[23];
    const float* Wf1 = (const float*)d_in[24];
    const float* bf1 = (const float*)d_in[25];
    const float* Wf2 = (const float*)d_in[26];
    const float* bf2 = (const float*)d_in[27];
    const float* Wf3 = (const float*)d_in[28];
    const float* bf3 = (const float*)d_in[29];
    float* outp = (float*)d_out;

    // ---- workspace bump allocator (~245 MB) ----
    char* base = (char*)d_ws;
    size_t off = 0;
    auto alloc = [&](size_t bytes) -> char* {
        char* p = base + off;
        off += (bytes + 255) & ~(size_t)255;
        return p;
    };
    u16* Whyp_b = (u16*)alloc((size_t)NCH * DH * D_INN * 2);
    u16* Wd_b   = (u16*)alloc((size_t)NCH * DH * DH * 2);
    u16* Wg1_b  = (u16*)alloc((size_t)NCH * DH * DH * 2);
    u16* Wg2_b  = (u16*)alloc((size_t)NCH * DH * DH * 2);
    u16* Wgate_b = (u16*)alloc((size_t)H3 * H3 * 2);
    u16* Wint_b  = (u16*)alloc((size_t)H3 * H3 * 2);
    u16* Wout_b  = (u16*)alloc((size_t)H3 * H3 * 2);
    u16* Wf1_b   = (u16*)alloc((size_t)1152 * H3 * 2);
    u16* Wf2_b   = (u16*)alloc((size_t)576 * 1152 * 2);
    u16* S_b = (u16*)alloc((size_t)NB * H3 * 2);
    u16* P_b = (u16*)alloc((size_t)NB * H3 * 2);
    const size_t NDB = (size_t)N_NODES * DH;       // per-channel elems
    u16* buf1 = (u16*)alloc(4 * NDB * 2);          // group ping
    u16* buf2 = (u16*)alloc(4 * NDB * 2);          // group pong
    u16* xhyp_b = (u16*)alloc((size_t)N_NODES * D_INN * 2);
    // batched CSR scratch (max group = 4 channels)
    int* cnt = (int*)alloc(4 * (size_t)N_NODES * 4);
    int* cursor = (int*)alloc(4 * (size_t)N_NODES * 4);
    int* rowptrA = (int*)alloc(4 * (size_t)(N_NODES + 1) * 4);
    int* rowptrE = (int*)alloc(4 * (size_t)(N_NODES + 1) * 4);
    int* psrcA = (int*)alloc(4 * (size_t)NE * 4);
    float* pvalA = (float*)alloc(4 * (size_t)NE * 4);
    int* psrcE = (int*)alloc(4 * (size_t)NE * 4);
    float* xhn = (float*)alloc((size_t)N_NODES * 4);
    float* hb = (float*)alloc((size_t)NCH * DH * 4);
    float* hb2 = (float*)alloc(NCH * 4);
    float* csum = (float*)alloc((size_t)4 * DH * 4);
    float* csq = (float*)alloc((size_t)4 * DH * 4);
    // stage-C overlays (GNN buffers dead by then)
    u16* G_b = buf1;                 // 37.75 MB <= 40.96
    float* h2f = (float*)buf2;       // 18.87 MB <= 40.96

    const int EG = (NE + 255) / 256;

    conv_w(W_hyp, Whyp_b, (size_t)NCH * DH * D_INN, stream);
    conv_w(Wd, Wd_b, (size_t)NCH * DH * DH, stream);
    conv_w(Wg1, Wg1_b, (size_t)NCH * DH * DH, stream);
    conv_w(Wg2, Wg2_b, (size_t)NCH * DH * DH, stream);
    conv_w(Wgate, Wgate_b, (size_t)H3 * H3, stream);
    conv_w(Wint, Wint_b, (size_t)H3 * H3, stream);
    conv_w(Wout, Wout_b, (size_t)H3 * H3, stream);
    conv_w(Wf1, Wf1_b, (size_t)1152 * H3, stream);
    conv_w(Wf2, Wf2_b, (size_t)576 * 1152, stream);

    k_expmap_proj_in<<<N_NODES, 256, 0, stream>>>(f1, xhyp_b, xhn);
    k_hb<<<NCH, 256, 0, stream>>>(b_hyp, hb, hb2);
    k_pair0<<<NB, 256, 0, stream>>>(edge_index, edge_id, f1, S_b, P_b);

    const int g0s[2] = {0, 4};
    const int gns[2] = {4, 3};
    for (int gi = 0; gi < 2; ++gi) {
        const int g0 = g0s[gi], G = gns[gi];
        const size_t eoff = (size_t)g0 * NE;
        // --- batched CSR builds (adj graph, then edge graph) ---
        k_izero<<<(G * N_NODES + 255) / 256, 256, 0, stream>>>(cnt, G * N_NODES);
        k_hist<<<dim3(EG, G), 256, 0, stream>>>(adj_dst + eoff, cnt, NE);
        k_scan<<<G, 256, 0, stream>>>(cnt, rowptrA, cursor);
        k_place_sv<<<dim3(EG, G), 256, 0, stream>>>(adj_src + eoff, adj_dst + eoff,
                                                    adj_val + eoff, cursor, psrcA, pvalA, NE);
        k_izero<<<(G * N_NODES + 255) / 256, 256, 0, stream>>>(cnt, G * N_NODES);
        k_hist<<<dim3(EG, G), 256, 0, stream>>>(edge_dst + eoff, cnt, NE);
        k_scan<<<G, 256, 0, stream>>>(cnt, rowptrE, cursor);
        k_place_s<<<dim3(EG, G), 256, 0, stream>>>(edge_src + eoff, edge_dst + eoff,
                                                   cursor, psrcE, NE);
        // --- batched pipeline ---
        // mx = x_hyp @ W_hyp[g].T -> buf1 (bf16)
        gemm_b(5, xhyp_b, Whyp_b + (size_t)g0 * DH * D_INN, nullptr, buf1, nullptr,
               N_NODES, DH, D_INN, G, 0, (size_t)DH * D_INN, NDB, 0, stream);
        k_rowfuse1<<<dim3(N_NODES, G), 256, 0, stream>>>(buf1, xhn, hb + g0 * DH, hb2 + g0);
        k_gather_fuse2<<<dim3(N_NODES, G), 256, 0, stream>>>(rowptrA, psrcA, pvalA, buf1, buf2);
        // d = u @ Wd.T + bd -> buf1
        gemm_b(5, buf2, Wd_b + (size_t)g0 * DH * DH, bd + g0 * DH, buf1, nullptr,
               N_NODES, DH, DH, G, NDB, (size_t)DH * DH, NDB, DH, stream);
        k_gather_add<<<dim3(N_NODES, G), 256, 0, stream>>>(rowptrE, psrcE, buf1, buf2);
        // z = agg @ Wg1.T + bg1 -> buf1
        gemm_b(5, buf2, Wg1_b + (size_t)g0 * DH * DH, bg1 + g0 * DH, buf1, nullptr,
               N_NODES, DH, DH, G, NDB, (size_t)DH * DH, NDB, DH, stream);
        k_zero<<<(G * DH + 255) / 256, 256, 0, stream>>>(csum, G * DH);
        k_zero<<<(G * DH + 255) / 256, 256, 0, stream>>>(csq, G * DH);
        k_colstats<<<dim3(200, G), 256, 0, stream>>>(buf1, csum, csq);
        k_normtanh<<<dim3(N_NODES, G), 256, 0, stream>>>(buf1, csum, csq,
                                                         gamma + g0 * DH, beta + g0 * DH);
        // z_ch = zt @ Wg2.T + bg2 -> buf2
        gemm_b(5, buf1, Wg2_b + (size_t)g0 * DH * DH, bg2 + g0 * DH, buf2, nullptr,
               N_NODES, DH, DH, G, NDB, (size_t)DH * DH, NDB, DH, stream);
        k_gather_ch<<<dim3(NB, G), 256, 0, stream>>>(edge_index, edge_id, buf2, S_b, P_b,
                                                     D_INN + g0 * DH);
    }

    // stage C (bf16 MFMA; gi->S_b, g->P_b, h1->G_b, h2->h2f)
    gemm_b(2, S_b, Wgate_b, bgate, G_b, nullptr, NB, H3, H3, 1, 0, 0, 0, 0, stream);
    gemm_b(4, P_b, Wint_b, bint, S_b, G_b, NB, H3, H3, 1, 0, 0, 0, 0, stream);
    gemm_b(5, S_b, Wout_b, bout, P_b, nullptr, NB, H3, H3, 1, 0, 0, 0, 0, stream);
    gemm_b(3, P_b, Wf1_b, bf1, G_b, nullptr, NB, 1152, H3, 1, 0, 0, 0, 0, stream);
    gemm_b(6, G_b, Wf2_b, bf2, h2f, nullptr, NB, 576, 1152, 1, 0, 0, 0, 0, stream);
    k_final<<<NB, 64, 0, stream>>>(h2f, Wf3, bf3, outp);
}